// Round 4
// baseline (6580.621 us; speedup 1.0000x reference)
//
#include <hip/hip_runtime.h>

static constexpr int HN = 512;
static constexpr float HINF = 1e9f;

// cost = sim + iou (exact fp32 add, matches jnp)
__global__ void cost_add_kernel(const float* __restrict__ sim,
                                const float* __restrict__ iou,
                                float* __restrict__ cost) {
    int idx = blockIdx.x * blockDim.x + threadIdx.x;
    if (idx < HN * HN / 4) {
        const float4* s4 = reinterpret_cast<const float4*>(sim);
        const float4* i4 = reinterpret_cast<const float4*>(iou);
        float4 a = s4[idx];
        float4 b = i4[idx];
        float4 c;
        c.x = a.x + b.x;
        c.y = a.y + b.y;
        c.z = a.z + b.z;
        c.w = a.w + b.w;
        reinterpret_cast<float4*>(cost)[idx] = c;
    }
}

// value-only wave-min step: combine with value shifted in from lower lanes
#define DPPMIN(ctrl)                                                                          \
    {                                                                                         \
        int _mi = __builtin_amdgcn_update_dpp(__float_as_int(m), __float_as_int(m), (ctrl),   \
                                              0xF, 0xF, false);                               \
        m = fminf(m, __int_as_float(_mi));                                                    \
    }

// Exact mirror of the reference JV (e-maxx) Hungarian on -cost. Single wave of 64 lanes,
// lane owns 8 consecutive cols. Inner loop defers ALL v/u dual updates to a phase-end
// replay (free cols' duals are bit-unchanged during a phase; used cols' duals are dead),
// leaving only the unconditional minv -= delta in the hot loop.
__global__ void __launch_bounds__(64, 1) hungarian_kernel(const float* __restrict__ cost,
                                                          float* __restrict__ out) {
    __shared__ float u_s[HN + 1];
    __shared__ int p2[HN];          // p2[j] = row (1-indexed) matched to col j+1; 0 = free
    __shared__ int way_t[HN];       // transposed: col c at [((c-1)&7)*64 + ((c-1)>>3)]
    __shared__ float delta_s[HN + 2];  // delta log, index by iteration t (1..T)
    __shared__ int mark_s[HN + 2];     // mark_s[col] = first iteration whose delta col's duals take

    const int lane = threadIdx.x;
    const int base = 8 * lane;  // cols base+1 .. base+8 (1-indexed)

    for (int k = lane; k <= HN; k += 64) u_s[k] = 0.0f;
    for (int k = lane; k < HN; k += 64) p2[k] = 0;
    __syncthreads();

    float v[8];
#pragma unroll
    for (int k = 0; k < 8; ++k) v[k] = 0.0f;

    int colsh[8];
#pragma unroll
    for (int k = 0; k < 8; ++k) colsh[k] = (base + k + 1) << 10;

    for (int i = 1; i <= HN; ++i) {
        // preload row i (i0 = p[0] = i)
        const float4* r4 = reinterpret_cast<const float4*>(cost + ((size_t)(i - 1) << 9));
        float4 ra = r4[2 * lane];
        float4 rb = r4[2 * lane + 1];

        // aligned vector gather of my cols' matched rows
        int4 pA = *reinterpret_cast<const int4*>(&p2[base]);
        int4 pB = *reinterpret_cast<const int4*>(&p2[base + 4]);
        int p8[8] = {pA.x, pA.y, pA.z, pA.w, pB.x, pB.y, pB.z, pB.w};
        int tjb[8];
#pragma unroll
        for (int k = 0; k < 8; ++k) tjb[k] = colsh[k] | p8[k];  // (col<<10)|matched row

        float u_start = u_s[i];  // phase-start u[i] (broadcast read)
        float u_cur = u_start;

        float minv[8];
        int way[8];
#pragma unroll
        for (int k = 0; k < 8; ++k) {
            minv[k] = HINF;
            way[k] = 0;
        }
        unsigned usedmask = 0u;
        int j0 = 0;
        int jfin = 0;
        int T = 0;

        while (true) {
            ++T;
            // mark j0 used (no-op when j0 == 0: shifted lane index matches nobody)
            unsigned km1 = (unsigned)(j0 - 1);
            if ((unsigned)lane == (km1 >> 3)) usedmask |= (1u << (km1 & 7u));

            float c8[8] = {ra.x, ra.y, ra.z, ra.w, rb.x, rb.y, rb.z, rb.w};
            float tv[8];
#pragma unroll
            for (int k = 0; k < 8; ++k) {
                float t = (-c8[k]) - u_cur;  // (costp - u), costp = -cost
                float cur = t - v[k];        // v[k] = phase-start value == current for free cols
                bool fr = !((usedmask >> k) & 1u);
                bool better = fr && (cur < minv[k]);
                minv[k] = better ? cur : minv[k];
                way[k] = better ? j0 : way[k];
                tv[k] = fr ? minv[k] : HINF;  // cand = where(free, minv, INF)
            }

            // local 8->1 first-min tree (strict <, left/lower-col wins ties)
            float av[4];
            int aj[4];
#pragma unroll
            for (int k = 0; k < 4; ++k) {
                bool r = tv[2 * k + 1] < tv[2 * k];
                av[k] = r ? tv[2 * k + 1] : tv[2 * k];
                aj[k] = r ? tjb[2 * k + 1] : tjb[2 * k];
            }
            float bv2[2];
            int bj2[2];
#pragma unroll
            for (int k = 0; k < 2; ++k) {
                bool r = av[2 * k + 1] < av[2 * k];
                bv2[k] = r ? av[2 * k + 1] : av[2 * k];
                bj2[k] = r ? aj[2 * k + 1] : aj[2 * k];
            }
            bool r0 = bv2[1] < bv2[0];
            float lv = r0 ? bv2[1] : bv2[0];
            int lj = r0 ? bj2[1] : bj2[0];

            // wave-wide min (value only), result in lane 63
            float m = lv;
            DPPMIN(0x111)  // row_shr:1
            DPPMIN(0x112)  // row_shr:2
            DPPMIN(0x114)  // row_shr:4
            DPPMIN(0x118)  // row_shr:8
            DPPMIN(0x142)  // row_bcast15
            DPPMIN(0x143)  // row_bcast31
            float gmin = __int_as_float(__builtin_amdgcn_readlane(__float_as_int(m), 63));

            // first lane achieving the min owns the global first argmin
            unsigned long long eq = __ballot(lv == gmin);
            int lanestar = __ffsll((unsigned long long)eq) - 1;
            int tj0 = __builtin_amdgcn_readlane(lj, lanestar);
            int j1 = tj0 >> 10;
            int prow = tj0 & 1023;

            // next row's data: clamped unconditional load (dead when prow==0)
            int rown = (prow != 0) ? prow : 1;
            const float4* q4 = reinterpret_cast<const float4*>(cost + ((size_t)(rown - 1) << 9));
            ra = q4[2 * lane];
            rb = q4[2 * lane + 1];
            float u_next = u_s[rown];  // phase-start u of entering row (broadcast, hidden)

            // log for the phase-end dual replay (uniform same-address writes collapse)
            delta_s[T] = gmin;
            mark_s[j1] = T + 1;  // col j1's duals take deltas (T+1 .. T_end); empty if j1 = jfin

            // only surviving in-loop dual update: minv -= delta, unconditional
            // (free cols: reference semantics; used cols: dead state under the fr guard)
#pragma unroll
            for (int k = 0; k < 8; ++k) minv[k] -= gmin;

            if (prow == 0) {
                jfin = j1;
                break;
            }
            j0 = j1;
            u_cur = u_next;
        }

        // dump way (conflict-free transposed)
#pragma unroll
        for (int k = 0; k < 8; ++k) way_t[k * 64 + lane] = way[k];
        __syncthreads();

        if (lane == 0) {
            // augment along the alternating path
            int jw = jfin;
            while (jw != 0) {
                int jn = way_t[((jw - 1) & 7) * 64 + ((jw - 1) >> 3)];
                p2[jw - 1] = (jn != 0) ? p2[jn - 1] : i;
                jw = jn;
            }
            // u[i] += delta_t for every t (col 0 used from iteration 1), sequential
            float ui = u_start;
            for (int t = 1; t <= T; ++t) ui += delta_s[t];
            u_s[i] = ui;
        }

        // replay deferred duals for my used cols: v[k] -= d_t, u[p8[k]] += d_t, in t order
        // (bit-identical sequence to the reference's per-iteration updates)
#pragma unroll
        for (int k = 0; k < 8; ++k) {
            if ((usedmask >> k) & 1u) {
                int tk = mark_s[base + k + 1];
                float uv = u_s[p8[k]];  // phase-start value (written only at phase end)
                float vv = v[k];
                for (int t = tk; t <= T; ++t) {
                    float d = delta_s[t];
                    vv -= d;
                    uv += d;
                }
                v[k] = vv;
                u_s[p8[k]] = uv;  // rows distinct across cols; != i
            }
        }
        __syncthreads();
    }

    // outputs: [cost (512x512)] [row_ind (512)] [col_ind (512)] as float32
    float* rowo = out + HN * HN;
    float* colo = rowo + HN;
#pragma unroll
    for (int k = 0; k < 8; ++k) {
        int r = base + k;
        rowo[r] = (float)r;
        int prow = p2[r];  // row matched to col r+1
        colo[prow - 1] = (float)r;
    }
}

extern "C" void kernel_launch(void* const* d_in, const int* in_sizes, int n_in,
                              void* d_out, int out_size, void* d_ws, size_t ws_size,
                              hipStream_t stream) {
    const float* sim = (const float*)d_in[0];
    const float* iou = (const float*)d_in[1];
    float* out = (float*)d_out;

    cost_add_kernel<<<(HN * HN / 4 + 255) / 256, 256, 0, stream>>>(sim, iou, out);
    hungarian_kernel<<<1, 64, 0, stream>>>(out, out);
}

// Round 5
// 4159.432 us; speedup vs baseline: 1.5821x; 1.5821x over previous
//
#include <hip/hip_runtime.h>

static constexpr int HN = 512;

// cost = sim + iou (exact fp32 add, matches jnp)
__global__ void cost_add_kernel(const float* __restrict__ sim,
                                const float* __restrict__ iou,
                                float* __restrict__ cost) {
    int idx = blockIdx.x * blockDim.x + threadIdx.x;
    if (idx < HN * HN / 4) {
        const float4* s4 = reinterpret_cast<const float4*>(sim);
        const float4* i4 = reinterpret_cast<const float4*>(iou);
        float4 a = s4[idx];
        float4 b = i4[idx];
        float4 c;
        c.x = a.x + b.x;
        c.y = a.y + b.y;
        c.z = a.z + b.z;
        c.w = a.w + b.w;
        reinterpret_cast<float4*>(cost)[idx] = c;
    }
}

// value-only wave-min step: combine with value shifted in from lower lanes
#define DPPMIN(ctrl)                                                                          \
    {                                                                                         \
        int _mi = __builtin_amdgcn_update_dpp(__float_as_int(m), __float_as_int(m), (ctrl),   \
                                              0xF, 0xF, false);                               \
        m = fminf(m, __int_as_float(_mi));                                                    \
    }

// Exact-decision mirror of the reference JV (e-maxx) Hungarian on -cost.
// Single wave, lane owns 8 consecutive cols. Used-col suppression via +inf absorption
// (minv[used]=inf stays inf under -=d; curG=cur+inf makes `better` false, freezing way).
// v/u duals accumulate in-loop via exact-product fma masks (bit-identical to the
// reference's where(used, d, 0) adds). No free-mask extraction in the hot loop.
__global__ void __launch_bounds__(64, 1) hungarian_kernel(const float* __restrict__ cost,
                                                          float* __restrict__ out) {
    __shared__ float u_s[HN + 1];
    __shared__ int p2[HN];     // p2[j] = row (1-indexed) matched to col j+1; 0 = free
    __shared__ int way_t[HN];  // transposed: col c at [((c-1)&7)*64 + ((c-1)>>3)]

    const int lane = threadIdx.x;
    const int base = 8 * lane;  // cols base+1 .. base+8 (1-indexed)
    const float INFP = __builtin_inff();

    for (int k = lane; k <= HN; k += 64) u_s[k] = 0.0f;
    for (int k = lane; k < HN; k += 64) p2[k] = 0;
    __syncthreads();

    float w[8];  // column duals v, live in registers across all phases
#pragma unroll
    for (int k = 0; k < 8; ++k) w[k] = 0.0f;

    int colsh[8];
#pragma unroll
    for (int k = 0; k < 8; ++k) colsh[k] = (base + k + 1) << 10;

    for (int i = 1; i <= HN; ++i) {
        // preload row i (i0 = p[0] = i)
        const float4* r4 = reinterpret_cast<const float4*>(cost + ((size_t)(i - 1) << 9));
        float4 ra = r4[2 * lane];
        float4 rb = r4[2 * lane + 1];

        // aligned vector gather of my cols' matched rows
        int4 pA = *reinterpret_cast<const int4*>(&p2[base]);
        int4 pB = *reinterpret_cast<const int4*>(&p2[base + 4]);
        int p8[8] = {pA.x, pA.y, pA.z, pA.w, pB.x, pB.y, pB.z, pB.w};
        int tjb[8];
#pragma unroll
        for (int k = 0; k < 8; ++k) tjb[k] = colsh[k] | p8[k];  // (col<<10)|matched row

        float u_own[8];
#pragma unroll
        for (int k = 0; k < 8; ++k) u_own[k] = u_s[p8[k]];  // phase-start duals of my rows

        float u_start = u_s[i];
        float u_cur = u_start;
        float u_i_run = u_start;

        float minv[8], mk[8], uINF[8];
        int way[8];
#pragma unroll
        for (int k = 0; k < 8; ++k) {
            minv[k] = INFP;
            mk[k] = 0.0f;
            uINF[k] = 0.0f;
            way[k] = 0;
        }
        int j0 = 0;
        int jfin = 0;

        while (true) {
            // mark previous winner j0 used (j0==0 -> km1 wraps, matches no col)
            unsigned km1 = (unsigned)(j0 - 1);
#pragma unroll
            for (int k = 0; k < 8; ++k) {
                bool hit = (km1 == (unsigned)(base + k));
                uINF[k] = hit ? INFP : uINF[k];
                minv[k] = hit ? INFP : minv[k];
                mk[k] = hit ? 1.0f : mk[k];
            }

            float c8[8] = {ra.x, ra.y, ra.z, ra.w, rb.x, rb.y, rb.z, rb.w};
#pragma unroll
            for (int k = 0; k < 8; ++k) {
                float t = c8[k] + u_cur;       // cur = -(c+u) - w  == (-c - u) - v exactly
                float cur = -t - w[k];
                float curG = cur + uINF[k];    // used col -> +inf (absorbs), free -> cur (+0.0)
                bool better = curG < minv[k];  // used: inf<inf = false -> way frozen
                minv[k] = better ? curG : minv[k];
                way[k] = better ? j0 : way[k];
            }

            // local 8->1 first-min tree (strict <, lower col wins ties)
            float av[4];
            int aj[4];
#pragma unroll
            for (int k = 0; k < 4; ++k) {
                bool r = minv[2 * k + 1] < minv[2 * k];
                av[k] = r ? minv[2 * k + 1] : minv[2 * k];
                aj[k] = r ? tjb[2 * k + 1] : tjb[2 * k];
            }
            float bv2[2];
            int bj2[2];
#pragma unroll
            for (int k = 0; k < 2; ++k) {
                bool r = av[2 * k + 1] < av[2 * k];
                bv2[k] = r ? av[2 * k + 1] : av[2 * k];
                bj2[k] = r ? aj[2 * k + 1] : aj[2 * k];
            }
            bool r0 = bv2[1] < bv2[0];
            float lv = r0 ? bv2[1] : bv2[0];
            int lj = r0 ? bj2[1] : bj2[0];

            // wave-wide value min, result in lane 63
            float m = lv;
            DPPMIN(0x111)  // row_shr:1
            DPPMIN(0x112)  // row_shr:2
            DPPMIN(0x114)  // row_shr:4
            DPPMIN(0x118)  // row_shr:8
            DPPMIN(0x142)  // row_bcast15
            DPPMIN(0x143)  // row_bcast31
            float gmin = __int_as_float(__builtin_amdgcn_readlane(__float_as_int(m), 63));

            // first lane achieving the min holds the global first argmin
            unsigned long long eq = __ballot(lv == gmin);
            int lanestar = __ffsll(eq) - 1;
            int tj0 = __builtin_amdgcn_readlane(lj, lanestar);
            int j1 = tj0 >> 10;
            int prow = tj0 & 1023;

            // issue next row's load + entering row's dual read early (hide latency)
            int rm1 = (prow > 0) ? (prow - 1) : 0;
            const float4* q4 = reinterpret_cast<const float4*>(cost + ((size_t)rm1 << 9));
            ra = q4[2 * lane];
            rb = q4[2 * lane + 1];
            float u_next = u_s[rm1 + 1];  // phase-invariant while its col was free

            // dual/bookkeeping updates in the load shadow
            float d = gmin;
            float nd = -d;
            u_i_run += d;
#pragma unroll
            for (int k = 0; k < 8; ++k) {
                minv[k] -= d;                       // free: ref semantics; used: inf stays inf
                w[k] = fmaf(mk[k], nd, w[k]);       // v -= where(used, d, 0)   (exact product)
                u_own[k] = fmaf(mk[k], d, u_own[k]);  // u[p] += where(used, d, 0)
            }

            if (prow == 0) {
                jfin = j1;
                break;
            }
            j0 = j1;
            u_cur = u_next;
        }

        // dump way (conflict-free transposed)
#pragma unroll
        for (int k = 0; k < 8; ++k) way_t[k * 64 + lane] = way[k];
        __syncthreads();

        // write back duals of used cols' matched rows (rows distinct, != i)
#pragma unroll
        for (int k = 0; k < 8; ++k) {
            if (mk[k] == 1.0f) u_s[p8[k]] = u_own[k];
        }
        if (lane == 0) {
            u_s[i] = u_i_run;
            // augment along the alternating path
            int jw = jfin;
            while (jw != 0) {
                int jn = way_t[((jw - 1) & 7) * 64 + ((jw - 1) >> 3)];
                p2[jw - 1] = (jn != 0) ? p2[jn - 1] : i;
                jw = jn;
            }
        }
        __syncthreads();
    }

    // outputs: [cost (512x512)] [row_ind (512)] [col_ind (512)] as float32
    float* rowo = out + HN * HN;
    float* colo = rowo + HN;
#pragma unroll
    for (int k = 0; k < 8; ++k) {
        int r = base + k;
        rowo[r] = (float)r;
        int prow = p2[r];  // row matched to col r+1
        colo[prow - 1] = (float)r;
    }
}

extern "C" void kernel_launch(void* const* d_in, const int* in_sizes, int n_in,
                              void* d_out, int out_size, void* d_ws, size_t ws_size,
                              hipStream_t stream) {
    const float* sim = (const float*)d_in[0];
    const float* iou = (const float*)d_in[1];
    float* out = (float*)d_out;

    cost_add_kernel<<<(HN * HN / 4 + 255) / 256, 256, 0, stream>>>(sim, iou, out);
    hungarian_kernel<<<1, 64, 0, stream>>>(out, out);
}

// Round 6
// 3925.614 us; speedup vs baseline: 1.6763x; 1.0596x over previous
//
#include <hip/hip_runtime.h>

static constexpr int HN = 512;

typedef float vf2 __attribute__((ext_vector_type(2)));

// cost = sim + iou (exact fp32 add, matches jnp)
__global__ void cost_add_kernel(const float* __restrict__ sim,
                                const float* __restrict__ iou,
                                float* __restrict__ cost) {
    int idx = blockIdx.x * blockDim.x + threadIdx.x;
    if (idx < HN * HN / 4) {
        const float4* s4 = reinterpret_cast<const float4*>(sim);
        const float4* i4 = reinterpret_cast<const float4*>(iou);
        float4 a = s4[idx];
        float4 b = i4[idx];
        float4 c;
        c.x = a.x + b.x;
        c.y = a.y + b.y;
        c.z = a.z + b.z;
        c.w = a.w + b.w;
        reinterpret_cast<float4*>(cost)[idx] = c;
    }
}

// value-only wave-min step: combine with value shifted in from lower lanes
#define DPPMIN(ctrl)                                                                          \
    {                                                                                         \
        int _mi = __builtin_amdgcn_update_dpp(__float_as_int(m), __float_as_int(m), (ctrl),   \
                                              0xF, 0xF, false);                               \
        m = fminf(m, __int_as_float(_mi));                                                    \
    }

// Exact-decision mirror of the reference JV (e-maxx) Hungarian on -cost.
// Single wave, lane owns 8 consecutive cols (as 4 float2 pairs for v_pk_* f32 math).
// Used-col suppression: compare-copy wc set to -INF at mark -> cur = -t - wc = +INF,
// which freezes minv (+INF) and way without any extra guard op. Live duals v (w2) and
// row duals (uo2) accumulate via exact-product packed fmas (bit-identical to the
// reference's where(used, d, 0) sequential adds).
__global__ void __launch_bounds__(64, 1) hungarian_kernel(const float* __restrict__ cost,
                                                          float* __restrict__ out) {
    __shared__ float u_s[HN + 1];
    __shared__ int p2[HN];     // p2[j] = row (1-indexed) matched to col j+1; 0 = free
    __shared__ int way_t[HN];  // transposed: col c at [((c-1)&7)*64 + ((c-1)>>3)]

    const int lane = threadIdx.x;
    const int base = 8 * lane;  // cols base+1 .. base+8 (1-indexed)
    const float INFP = __builtin_inff();
    const float NINF = -__builtin_inff();

    for (int k = lane; k <= HN; k += 64) u_s[k] = 0.0f;
    for (int k = lane; k < HN; k += 64) p2[k] = 0;
    __syncthreads();

    vf2 w2[4];  // column duals v, live across all phases
#pragma unroll
    for (int p = 0; p < 4; ++p) w2[p] = (vf2){0.0f, 0.0f};

    int colsh[8];
#pragma unroll
    for (int k = 0; k < 8; ++k) colsh[k] = (base + k + 1) << 10;

    for (int i = 1; i <= HN; ++i) {
        // preload row i (i0 = p[0] = i)
        const float4* r4 = reinterpret_cast<const float4*>(cost + ((size_t)(i - 1) << 9));
        float4 ra = r4[2 * lane];
        float4 rb = r4[2 * lane + 1];

        // aligned vector gather of my cols' matched rows
        int4 pA = *reinterpret_cast<const int4*>(&p2[base]);
        int4 pB = *reinterpret_cast<const int4*>(&p2[base + 4]);
        int p8[8] = {pA.x, pA.y, pA.z, pA.w, pB.x, pB.y, pB.z, pB.w};
        int tjb[8];
#pragma unroll
        for (int k = 0; k < 8; ++k) tjb[k] = colsh[k] | p8[k];  // (col<<10)|matched row

        vf2 uo2[4];  // phase-start duals of my cols' matched rows
#pragma unroll
        for (int p = 0; p < 4; ++p) {
            uo2[p].x = u_s[p8[2 * p]];
            uo2[p].y = u_s[p8[2 * p + 1]];
        }

        float u_start = u_s[i];
        float u_cur = u_start;
        float u_i_run = u_start;

        vf2 wc2[4], mnv2[4], mk2[4];
        int way[8];
#pragma unroll
        for (int p = 0; p < 4; ++p) {
            wc2[p] = w2[p];  // free cols: bitwise == w2 all phase (fma adds 0)
            mnv2[p] = (vf2){INFP, INFP};
            mk2[p] = (vf2){0.0f, 0.0f};
        }
#pragma unroll
        for (int k = 0; k < 8; ++k) way[k] = 0;

        int jprev = 0;  // j0: col whose row we are expanding; 0 = virtual start
        int jfin = 0;

        while (true) {
            // mark jprev used (jprev==0 -> j1s==0 matches no colsh, all >= 1<<10)
            unsigned j1s = (unsigned)(jprev << 10);
#pragma unroll
            for (int k = 0; k < 8; ++k) {
                bool hit = ((unsigned)colsh[k] == j1s);
                if (k & 1) {
                    wc2[k >> 1].y = hit ? NINF : wc2[k >> 1].y;
                    mnv2[k >> 1].y = hit ? INFP : mnv2[k >> 1].y;
                    mk2[k >> 1].y = hit ? 1.0f : mk2[k >> 1].y;
                } else {
                    wc2[k >> 1].x = hit ? NINF : wc2[k >> 1].x;
                    mnv2[k >> 1].x = hit ? INFP : mnv2[k >> 1].x;
                    mk2[k >> 1].x = hit ? 1.0f : mk2[k >> 1].x;
                }
            }

            // cur = ((-c) - u) - v via packed math; used cols -> +INF (wc = -INF)
            vf2 u2;
            u2.x = u_cur;
            u2.y = u_cur;
            vf2 cc[4];
            cc[0].x = ra.x; cc[0].y = ra.y;
            cc[1].x = ra.z; cc[1].y = ra.w;
            cc[2].x = rb.x; cc[2].y = rb.y;
            cc[3].x = rb.z; cc[3].y = rb.w;
#pragma unroll
            for (int p = 0; p < 4; ++p) {
                vf2 t = cc[p] + u2;        // v_pk_add_f32
                vf2 cur = (-t) - wc2[p];   // v_pk_add_f32 with neg mods; -(c+u) == (-c)-u exactly
                bool b0 = cur.x < mnv2[p].x;  // used: +INF < +INF = false -> frozen
                bool b1 = cur.y < mnv2[p].y;
                mnv2[p].x = b0 ? cur.x : mnv2[p].x;
                mnv2[p].y = b1 ? cur.y : mnv2[p].y;
                way[2 * p] = b0 ? jprev : way[2 * p];
                way[2 * p + 1] = b1 ? jprev : way[2 * p + 1];
            }

            // local 8->1 first-min tree (strict <, lower col wins ties)
            float mv[8] = {mnv2[0].x, mnv2[0].y, mnv2[1].x, mnv2[1].y,
                           mnv2[2].x, mnv2[2].y, mnv2[3].x, mnv2[3].y};
            float av[4];
            int aj[4];
#pragma unroll
            for (int k = 0; k < 4; ++k) {
                bool r = mv[2 * k + 1] < mv[2 * k];
                av[k] = r ? mv[2 * k + 1] : mv[2 * k];
                aj[k] = r ? tjb[2 * k + 1] : tjb[2 * k];
            }
            float bv2[2];
            int bj2[2];
#pragma unroll
            for (int k = 0; k < 2; ++k) {
                bool r = av[2 * k + 1] < av[2 * k];
                bv2[k] = r ? av[2 * k + 1] : av[2 * k];
                bj2[k] = r ? aj[2 * k + 1] : aj[2 * k];
            }
            bool r0 = bv2[1] < bv2[0];
            float lv = r0 ? bv2[1] : bv2[0];
            int lj = r0 ? bj2[1] : bj2[0];

            // wave-wide value min, result in lane 63
            float m = lv;
            DPPMIN(0x111)  // row_shr:1
            DPPMIN(0x112)  // row_shr:2
            DPPMIN(0x114)  // row_shr:4
            DPPMIN(0x118)  // row_shr:8
            DPPMIN(0x142)  // row_bcast15
            DPPMIN(0x143)  // row_bcast31
            float gmin = __int_as_float(__builtin_amdgcn_readlane(__float_as_int(m), 63));

            // first lane achieving the min holds the global first argmin
            unsigned long long eq = __ballot(lv == gmin);
            int lanestar = __ffsll(eq) - 1;
            int tj0 = __builtin_amdgcn_readlane(lj, lanestar);
            int j1 = tj0 >> 10;
            int prow = tj0 & 1023;

            // issue next row's load + entering row's dual read early (hide L2 latency)
            int rm1 = (prow > 0) ? (prow - 1) : 0;
            const float4* q4 = reinterpret_cast<const float4*>(cost + ((size_t)rm1 << 9));
            ra = q4[2 * lane];
            rb = q4[2 * lane + 1];
            float u_next = u_s[rm1 + 1];  // phase-invariant while its col was free

            // dual/bookkeeping updates in the load shadow (packed, bit-exact)
            vf2 d2;
            d2.x = gmin;
            d2.y = gmin;
            vf2 nd2 = -d2;
            u_i_run += gmin;
#pragma unroll
            for (int p = 0; p < 4; ++p) {
                mnv2[p] = mnv2[p] - d2;  // free: ref semantics; used: inf stays inf
                w2[p] = __builtin_elementwise_fma(mk2[p], nd2, w2[p]);   // v -= where(used,d,0)
                uo2[p] = __builtin_elementwise_fma(mk2[p], d2, uo2[p]);  // u[p] += where(used,d,0)
            }

            if (prow == 0) {
                jfin = j1;
                break;
            }
            jprev = j1;
            u_cur = u_next;
        }

        // dump way (conflict-free transposed)
#pragma unroll
        for (int k = 0; k < 8; ++k) way_t[k * 64 + lane] = way[k];
        __syncthreads();

        // write back duals of used cols' matched rows (rows distinct, != i)
#pragma unroll
        for (int p = 0; p < 4; ++p) {
            if (mk2[p].x == 1.0f) u_s[p8[2 * p]] = uo2[p].x;
            if (mk2[p].y == 1.0f) u_s[p8[2 * p + 1]] = uo2[p].y;
        }
        if (lane == 0) {
            u_s[i] = u_i_run;
            // augment along the alternating path
            int jw = jfin;
            while (jw != 0) {
                int jn = way_t[((jw - 1) & 7) * 64 + ((jw - 1) >> 3)];
                p2[jw - 1] = (jn != 0) ? p2[jn - 1] : i;
                jw = jn;
            }
        }
        __syncthreads();
    }

    // outputs: [cost (512x512)] [row_ind (512)] [col_ind (512)] as float32
    float* rowo = out + HN * HN;
    float* colo = rowo + HN;
#pragma unroll
    for (int k = 0; k < 8; ++k) {
        int r = base + k;
        rowo[r] = (float)r;
        int prow = p2[r];  // row matched to col r+1
        colo[prow - 1] = (float)r;
    }
}

extern "C" void kernel_launch(void* const* d_in, const int* in_sizes, int n_in,
                              void* d_out, int out_size, void* d_ws, size_t ws_size,
                              hipStream_t stream) {
    const float* sim = (const float*)d_in[0];
    const float* iou = (const float*)d_in[1];
    float* out = (float*)d_out;

    cost_add_kernel<<<(HN * HN / 4 + 255) / 256, 256, 0, stream>>>(sim, iou, out);
    hungarian_kernel<<<1, 64, 0, stream>>>(out, out);
}